// Round 2
// baseline (808.080 us; speedup 1.0000x reference)
//
#include <hip/hip_runtime.h>
#include <math.h>

#define B_ 4096
#define F_ 32
#define T_ 100
#define H_ 512
#define C_ 8
#define D_ 256

static __device__ __constant__ float BETA_F = 0.95122942450071400910f; // exp(-0.05) rounded to f32

// Transpose W1 (H,D) -> W1T (D,H) and W2 (C,H) -> W2T (H,C) into workspace.
__global__ void snn_prep(const float* __restrict__ W1,
                         const float* __restrict__ W2,
                         float* __restrict__ ws) {
    float* W1T = ws;                         // D_*H_ floats
    float* W2T = ws + (size_t)D_ * H_;       // H_*C_ floats
    const int bid = blockIdx.x;
    const int tid = threadIdx.x;             // 256 threads
    if (bid < D_) {
        const int d = bid;
        W1T[(size_t)d * H_ + tid]       = W1[(size_t)tid * D_ + d];
        W1T[(size_t)d * H_ + tid + 256] = W1[(size_t)(tid + 256) * D_ + d];
    } else {
        for (int h = tid; h < H_; h += 256) {
#pragma unroll
            for (int c = 0; c < C_; ++c)
                W2T[h * C_ + c] = W2[c * H_ + h];
        }
    }
}

// One wave (64 lanes) per batch element.
// Lane owns h = lane + 64*i (i=0..7) and d = lane + 64*i (i=0..3) for encoding.
__global__ __launch_bounds__(64)
void snn_main(const float* __restrict__ spec,   // (B,F)
              const float* __restrict__ ws,     // W1T | W2T
              const float* __restrict__ noise,  // (B,T,D)
              float* __restrict__ out) {        // (B,C)
    const int b = blockIdx.x;
    const int lane = threadIdx.x;

    __shared__ unsigned long long s1mask[T_][8]; // word i: bit l <-> h = 64*i + l
    __shared__ float u_lds[T_][C_];

    const float* __restrict__ W1T = ws;
    const float* __restrict__ W2T = ws + (size_t)D_ * H_;
    const float* __restrict__ NZb = noise + (size_t)b * T_ * D_;

    // ---- encoder activations for this lane's 4 d's (d = lane + 64*i) ----
    float pr[4];
#pragma unroll
    for (int i = 0; i < 4; ++i) {
        const int d = lane + 64 * i;
        const int f = d >> 3, n = d & 7;
        const float s = spec[b * F_ + f];
        const float p = (float)((double)n / 7.0);   // matches np.linspace(0,1,8)
        const float diff = s - p;                    // f32, as reference
        const float arg = -32.0f * (diff * diff);    // exact scale (1/(2*TW^2)=32)
        pr[i] = (float)exp((double)arg) * 0.1f;      // correctly-rounded f32 exp
    }

    float m1[8];
#pragma unroll
    for (int i = 0; i < 8; ++i) m1[i] = 0.f;

    // prefetch noise for t=0 (4 coalesced dword loads, d-ascending words)
    float nz0 = NZb[lane], nz1 = NZb[64 + lane], nz2 = NZb[128 + lane], nz3 = NZb[192 + lane];

    for (int t = 0; t < T_; ++t) {
        // prefetch next timestep's noise (clamped to avoid OOB)
        const int tn = (t + 1 < T_) ? (t + 1) : t;
        const float* np_ = NZb + (size_t)tn * D_;
        const float nn0 = np_[lane], nn1 = np_[64 + lane], nn2 = np_[128 + lane], nn3 = np_[192 + lane];

        // spike masks, bit k of bmI <-> d = 64*I + k  (ascending-d words)
        unsigned long long bm0 = __ballot(nz0 < pr[0]);
        unsigned long long bm1 = __ballot(nz1 < pr[1]);
        unsigned long long bm2 = __ballot(nz2 < pr[2]);
        unsigned long long bm3 = __ballot(nz3 < pr[3]);
        nz0 = nn0; nz1 = nn1; nz2 = nn2; nz3 = nn3;

        float z[8];
#pragma unroll
        for (int i = 0; i < 8; ++i) z[i] = 0.f;

        // pop events in ascending d (matches serial-k BLAS accumulation order)
        auto POP = [&]() -> int {
            if (bm0) { const int k = __builtin_ctzll(bm0); bm0 &= bm0 - 1; return k; }
            if (bm1) { const int k = __builtin_ctzll(bm1); bm1 &= bm1 - 1; return 64 + k; }
            if (bm2) { const int k = __builtin_ctzll(bm2); bm2 &= bm2 - 1; return 128 + k; }
            if (bm3) { const int k = __builtin_ctzll(bm3); bm3 &= bm3 - 1; return 192 + k; }
            return -1;
        };

        // depth-2 software pipeline over spike events (hide L2 latency)
        int da = POP();
        if (da >= 0) {
            const float* ra = W1T + (size_t)da * H_ + lane;
            float wa[8];
#pragma unroll
            for (int i = 0; i < 8; ++i) wa[i] = ra[64 * i];
            int db = POP();
            while (db >= 0) {
                const float* rb = W1T + (size_t)db * H_ + lane;
                float wb[8];
#pragma unroll
                for (int i = 0; i < 8; ++i) wb[i] = rb[64 * i];
#pragma unroll
                for (int i = 0; i < 8; ++i) z[i] += wa[i];
#pragma unroll
                for (int i = 0; i < 8; ++i) wa[i] = wb[i];
                db = POP();
            }
#pragma unroll
            for (int i = 0; i < 8; ++i) z[i] += wa[i];
        }

        // membrane update, threshold, reset; ballot s1 into LDS
        unsigned long long sb[8];
#pragma unroll
        for (int i = 0; i < 8; ++i) {
            const float mm = __fadd_rn(__fmul_rn(BETA_F, m1[i]), z[i]);
            const bool s = mm > 1.0f;
            sb[i] = __ballot(s);
            m1[i] = s ? 0.f : mm;
        }
        if (lane == 0) {
#pragma unroll
            for (int i = 0; i < 8; ++i) s1mask[t][i] = sb[i];
        }
    }

    __syncthreads();

    // ---- layer 2 drive: u[t][c] = s1[t] @ W2T, t-parallel across lanes ----
#pragma unroll
    for (int rep = 0; rep < 2; ++rep) {
        const int t = lane + rep * 64;
        if (t < T_) {
            unsigned long long sm[8];
#pragma unroll
            for (int j = 0; j < 8; ++j) sm[j] = s1mask[t][j];
            float u[8];
#pragma unroll
            for (int c = 0; c < 8; ++c) u[c] = 0.f;
#pragma unroll
            for (int j = 0; j < 8; ++j) {          // ascending h: word j covers [64j, 64j+64)
                unsigned long long m = sm[j];
                while (m) {
                    const int k = __builtin_ctzll(m);
                    m &= m - 1;
                    const int h = 64 * j + k;
                    const float4 wlo = ((const float4*)(W2T + h * 8))[0];
                    const float4 whi = ((const float4*)(W2T + h * 8))[1];
                    u[0] += wlo.x; u[1] += wlo.y; u[2] += wlo.z; u[3] += wlo.w;
                    u[4] += whi.x; u[5] += whi.y; u[6] += whi.z; u[7] += whi.w;
                }
            }
#pragma unroll
            for (int c = 0; c < 8; ++c) u_lds[t][c] = u[c];
        }
    }

    __syncthreads();

    // ---- serial m2 scan + spike count ----
    if (lane < 8) {
        float m2 = 0.f, acc = 0.f;
        for (int t = 0; t < T_; ++t) {
            const float uu = u_lds[t][lane];
            float mm = __fadd_rn(__fmul_rn(BETA_F, m2), uu);
            if (mm > 1.0f) { acc += 1.f; mm = 0.f; }
            m2 = mm;
        }
        out[b * C_ + lane] = acc / 100.0f;
    }
}

extern "C" void kernel_launch(void* const* d_in, const int* in_sizes, int n_in,
                              void* d_out, int out_size, void* d_ws, size_t ws_size,
                              hipStream_t stream) {
    const float* spec  = (const float*)d_in[0];  // (4096, 32)
    const float* W1    = (const float*)d_in[1];  // (512, 256)
    const float* W2    = (const float*)d_in[2];  // (8, 512)
    const float* noise = (const float*)d_in[3];  // (4096, 100, 256)
    float* out = (float*)d_out;                  // (4096, 8)
    float* ws  = (float*)d_ws;                   // >= (256*512 + 512*8)*4 bytes

    snn_prep<<<dim3(D_ + 1), dim3(256), 0, stream>>>(W1, W2, ws);
    snn_main<<<dim3(B_), dim3(64), 0, stream>>>(spec, ws, noise, out);
}